// Round 16
// baseline (44.494 us; speedup 1.0000x reference)
//
#include <hip/hip_runtime.h>
#include <hip/hip_bf16.h>

#define B_N   4096
#define DIM   512
#define NCLS  100
#define MARGIN 0.1f
#define ONE_EPS (1.0f - 1e-5f)
#define K_POS (-2.885390082f)   // -2  * log2(e)
#define K_NEG (57.70780163f)    //  40 * log2(e)
#define BIGF  3.0e38f

typedef __attribute__((ext_vector_type(8))) short short8;   // 8 bf16 = 4 VGPRs (MFMA A/B frag)
typedef __attribute__((ext_vector_type(4))) float f32x4;    // MFMA C/D frag
typedef unsigned short ushort_t;
typedef unsigned char  uchar_t;

__device__ __forceinline__ void async_load16(const void* g, void* l) {
    __builtin_amdgcn_global_load_lds(
        (const __attribute__((address_space(1))) unsigned int*)g,
        (__attribute__((address_space(3))) unsigned int*)l,
        16, 0, 0);
}

// ---------- K1: normalize rows -> bf16 + one-hot -> u8; ONE WAVE PER ROW ----------
__global__ __launch_bounds__(512) void prep_kernel(
    const float* __restrict__ feats, const float* __restrict__ labels,
    ushort_t* __restrict__ fn, uchar_t* __restrict__ lab8, float* __restrict__ out)
{
    const int row = blockIdx.x * 8 + (threadIdx.x >> 6);
    const int l = threadIdx.x & 63;
    const float4* fr = (const float4*)(feats + (size_t)row * DIM);
    const float4 a = fr[2 * l];
    const float4 b = fr[2 * l + 1];
    float ss = (a.x * a.x + a.y * a.y) + (a.z * a.z + a.w * a.w)
             + (b.x * b.x + b.y * b.y) + (b.z * b.z + b.w * b.w);
#pragma unroll
    for (int m = 32; m; m >>= 1) ss += __shfl_xor(ss, m, 64);
    const float sc = rsqrtf(ss);

    const float v[8] = {a.x, a.y, a.z, a.w, b.x, b.y, b.z, b.w};
    unsigned o[4];
#pragma unroll
    for (int k = 0; k < 4; ++k) {
        __hip_bfloat16 lo = __float2bfloat16(v[2 * k] * sc);
        __hip_bfloat16 hi = __float2bfloat16(v[2 * k + 1] * sc);
        o[k] = (unsigned)*(ushort_t*)&lo | ((unsigned)*(ushort_t*)&hi << 16);
    }
    uint4* dst = (uint4*)(fn + (size_t)row * DIM);
    dst[l] = make_uint4(o[0], o[1], o[2], o[3]);

    if (l < 25) {
        const float4 lb = ((const float4*)(labels + (size_t)row * NCLS))[l];
        const float lv[4] = {lb.x, lb.y, lb.z, lb.w};
#pragma unroll
        for (int k = 0; k < 4; ++k)
            if (lv[k] > 0.5f) lab8[row] = (uchar_t)(l * 4 + k);
    }
    if (blockIdx.x == 0 && threadIdx.x == 0) out[0] = 0.0f;
}

// ---------- K2: fused sim-GEMM + symmetric column-stats ----------
// R15 structure (128x128, 512 thr, 8 waves 2x4, 64x32/wave, triple-buffered
// LDS, counted vmcnt across barriers) + T5: s_setprio(1) around the MFMA
// cluster (pays when co-resident blocks' waves are at staggered phases).
#define BM 128
#define BK 32
#define NKSTEP (DIM / BK)   // 16

__global__ __launch_bounds__(512) void gemm_sim(
    const ushort_t* __restrict__ F, const uchar_t* __restrict__ lab8,
    float* __restrict__ part_f)   // [4096 cols][64 widx=by*2+wr][4] {pmin,psum,negmax,nsum}
{
    // XCD-aware bijective swizzle: 1024 blocks, 8 XCDs, 128 blocks/XCD chunk.
    const int bid = (int)blockIdx.x;
    const int swz = (bid & 7) * 128 + (bid >> 3);
    const int bx = swz & 31, by = swz >> 5;
    const int brow = by * BM, bcol = bx * BM;
    const bool bdiag = (bx == by);

    __shared__ __align__(16) ushort_t sA[3][BM * BK];
    __shared__ __align__(16) ushort_t sB[3][BM * BK];
    const int t = threadIdx.x;
    const int w = t >> 6, l = t & 63;
    const int wr = w >> 2, wc = w & 3;          // 2x4 waves -> 64x32 each

    f32x4 acc[4][2];
    const f32x4 fz = {0.f, 0.f, 0.f, 0.f};
#pragma unroll
    for (int m = 0; m < 4; ++m)
#pragma unroll
        for (int n = 0; n < 2; ++n) acc[m][n] = fz;

    // one async 16B load per thread per matrix (2 vmem ops/wave per stage);
    // LDS linear [row][32], source pre-swizzled (reads use slot ^ ((row>>1)&3))
    auto stage = [&](int buf, int kb) {
        const int row = t >> 2, slot = t & 3;
        const int kc  = slot ^ ((row >> 1) & 3);
        async_load16(F + (size_t)(brow + row) * DIM + kb + kc * 8, &sA[buf][t * 8]);
        async_load16(F + (size_t)(bcol + row) * DIM + kb + kc * 8, &sB[buf][t * 8]);
    };

    // prologue: tiles 0 and 1 in flight; retire tile 0 (oldest 2), keep tile 1 flying
    stage(0, 0);
    stage(1, BK);
    asm volatile("s_waitcnt vmcnt(2)\n\ts_barrier" ::: "memory");

#pragma unroll
    for (int ks = 0; ks < NKSTEP; ++ks) {
        const int cur = ks % 3;
        if (ks + 2 < NKSTEP) stage((ks + 2) % 3, (ks + 2) * BK);
        short8 av[4], bv[2];
#pragma unroll
        for (int m = 0; m < 4; ++m) {
            const int r    = wr * 64 + m * 16 + (l & 15);
            const int slot = (l >> 4) ^ ((r >> 1) & 3);
            av[m] = *(const short8*)&sA[cur][r * BK + slot * 8];
        }
#pragma unroll
        for (int n = 0; n < 2; ++n) {
            const int r    = wc * 32 + n * 16 + (l & 15);
            const int slot = (l >> 4) ^ ((r >> 1) & 3);
            bv[n] = *(const short8*)&sB[cur][r * BK + slot * 8];
        }
        __builtin_amdgcn_s_setprio(1);
#pragma unroll
        for (int m = 0; m < 4; ++m)
#pragma unroll
            for (int n = 0; n < 2; ++n)
                acc[m][n] = __builtin_amdgcn_mfma_f32_16x16x32_bf16(av[m], bv[n], acc[m][n], 0, 0, 0);
        __builtin_amdgcn_s_setprio(0);

        // barrier: tile ks+1 must be landed (all waves), tile ks+2 stays in flight
        if (ks < NKSTEP - 2) {
            asm volatile("s_waitcnt vmcnt(2) lgkmcnt(0)\n\ts_barrier" ::: "memory");
        } else if (ks < NKSTEP - 1) {
            asm volatile("s_waitcnt vmcnt(0) lgkmcnt(0)\n\ts_barrier" ::: "memory");
        }
        // last iteration: epilogue touches no LDS -> no barrier needed
    }

    // ---- epilogue: per-COLUMN stats (== per-row stats by symmetry) ----
    // C/D layout: col = wc*32 + n*16 + (l&15); rows = wr*64 + m*16 + g*4 + r
    const int g = l >> 4, c = l & 15;
    const bool hi4 = g & 1, hi5 = (g >> 1) & 1;
    const int widx = by * 2 + wr;

    int rl[4][4];
#pragma unroll
    for (int m = 0; m < 4; ++m) {
        const uchar4 r4 = *(const uchar4*)(lab8 + brow + wr * 64 + m * 16 + g * 4);
        rl[m][0] = r4.x; rl[m][1] = r4.y; rl[m][2] = r4.z; rl[m][3] = r4.w;
    }
    const int growb = brow + wr * 64 + g * 4;   // + m*16 + r gives the global row

#pragma unroll
    for (int n = 0; n < 2; ++n) {
        const int gcol = bcol + wc * 32 + n * 16 + c;
        const int cl = (int)lab8[gcol];
        float pm = BIGF, nm = -BIGF, ps = 0.f, ns = 0.f;
#pragma unroll
        for (int m = 0; m < 4; ++m)
#pragma unroll
            for (int r = 0; r < 4; ++r) {
                const float s = acc[m][n][r];
                const bool same = (rl[m][r] == cl);
                const float e = __builtin_amdgcn_exp2f((same ? K_POS : K_NEG) * (s - 0.5f));
                const bool excl = bdiag && (growb + m * 16 + r == gcol);
                if (same) {
                    if (s < ONE_EPS && !excl) { pm = fminf(pm, s); ps += e; }
                } else {
                    nm = fmaxf(nm, s); ns += e;
                }
            }
        // packed reduce-scatter over g (masks 16,32): lane-g ends with
        // quantity q==g of [pm, ps, nm, ns], fully reduced over 64 rows
        float sa = hi4 ? pm : ps;
        float sb = hi4 ? nm : ns;
        const float ra = __shfl_xor(sa, 16, 64);
        const float rb = __shfl_xor(sb, 16, 64);
        const float a = hi4 ? (ps + ra) : fminf(pm, ra);
        const float b = hi4 ? (ns + rb) : fmaxf(nm, rb);
        float sc_ = hi5 ? a : b;
        const float rc = __shfl_xor(sc_, 32, 64);
        const float v = hi5 ? (hi4 ? (b + rc) : fmaxf(b, rc))
                            : (hi4 ? (a + rc) : fminf(a, rc));
        part_f[((size_t)gcol * 64 + widx) * 4 + g] = v;
    }
}

// ---------- K3: one wave per row: merge 64 partials -> row loss ----------
__global__ __launch_bounds__(256) void row_finish(
    const float4* __restrict__ part, float* __restrict__ rowloss)
{
    const int g = threadIdx.x >> 6, j = threadIdx.x & 63;
    const int i = blockIdx.x * 4 + g;
    const float4 p = part[(size_t)i * 64 + j];
    float pm = p.x, ps = p.y, nm = p.z, ns = p.w;
#pragma unroll
    for (int m = 32; m; m >>= 1) {
        pm = fminf(pm, __shfl_xor(pm, m, 64));
        nm = fmaxf(nm, __shfl_xor(nm, m, 64));
        ps += __shfl_xor(ps, m, 64);
        ns += __shfl_xor(ns, m, 64);
    }
    if (j == 0) {
        // any neg kept <=> nm + margin > pm (then neg_max = nm);
        // any pos kept <=> pm - margin < neg_max
        const bool anyneg = (nm + MARGIN > pm);
        const bool valid  = anyneg && (pm - MARGIN < nm);
        rowloss[i] = valid ? (log1pf(ps) * 0.5f + log1pf(ns) * 0.025f) : 0.0f;
    }
}

// ---------- K4: sum rowloss -> out[0] (single block, no atomics) ----------
__global__ __launch_bounds__(256) void final_reduce(
    const float* __restrict__ rowloss, float* __restrict__ out)
{
    __shared__ float red[4];
    const int t = threadIdx.x;
    const float4* rp = (const float4*)rowloss;
    float v = 0.f;
#pragma unroll
    for (int q = 0; q < 4; ++q) {
        const float4 a = rp[t + 256 * q];
        v += (a.x + a.y) + (a.z + a.w);
    }
#pragma unroll
    for (int m = 32; m; m >>= 1) v += __shfl_xor(v, m, 64);
    if ((t & 63) == 0) red[t >> 6] = v;
    __syncthreads();
    if (t == 0) out[0] = (red[0] + red[1] + red[2] + red[3]) * (1.0f / (float)B_N);
}

extern "C" void kernel_launch(void* const* d_in, const int* in_sizes, int n_in,
                              void* d_out, int out_size, void* d_ws, size_t ws_size,
                              hipStream_t stream) {
    const float* feats  = (const float*)d_in[0];
    const float* labels = (const float*)d_in[1];
    float* out = (float*)d_out;

    // ws: part float[4096*64*4] = 4MB | fnorm bf16 4MB | lab u8 4KB | rowloss 16KB
    char* ws = (char*)d_ws;
    float*    part_f  = (float*)ws;
    ushort_t* fn      = (ushort_t*)(ws + (size_t)B_N * 64 * 16);
    uchar_t*  lab8    = (uchar_t*) (ws + (size_t)B_N * 64 * 16 + (size_t)B_N * DIM * 2);
    float*    rowloss = (float*)   (ws + (size_t)B_N * 64 * 16 + (size_t)B_N * DIM * 2 + (size_t)B_N);

    prep_kernel<<<B_N / 8, 512, 0, stream>>>(feats, labels, fn, lab8, out);
    gemm_sim<<<(B_N / BM) * (B_N / BM), 512, 0, stream>>>(fn, lab8, part_f);
    row_finish<<<B_N / 4, 256, 0, stream>>>((const float4*)part_f, rowloss);
    final_reduce<<<1, 256, 0, stream>>>(rowloss, out);
}

// Round 17
// 42.749 us; speedup vs baseline: 1.0408x; 1.0408x over previous
//
#include <hip/hip_runtime.h>
#include <hip/hip_bf16.h>
#include <hip/hip_fp8.h>

#define B_N   4096
#define DIM   512
#define NCLS  100
#define MARGIN 0.1f
#define ONE_EPS (1.0f - 1e-5f)
#define K_POS (-2.885390082f)   // -2  * log2(e)
#define K_NEG (57.70780163f)    //  40 * log2(e)
#define BIGF  3.0e38f

typedef __attribute__((ext_vector_type(4))) float f32x4;    // MFMA C/D frag
typedef __attribute__((ext_vector_type(8))) int   int8v;    // 32 fp8 = 8 VGPRs (A/B frag)
typedef unsigned short ushort_t;
typedef unsigned char  uchar_t;

#define SCL_16TH 123   // e8m0: 2^(123-127) = 1/16; both operands -> 2^-8 total

__device__ __forceinline__ void async_load16(const void* g, void* l) {
    __builtin_amdgcn_global_load_lds(
        (const __attribute__((address_space(1))) unsigned int*)g,
        (__attribute__((address_space(3))) unsigned int*)l,
        16, 0, 0);
}

// ---------- K1: normalize rows -> fp8 e4m3 (x16) + one-hot -> u8; wave per row ----------
__global__ __launch_bounds__(512) void prep_kernel(
    const float* __restrict__ feats, const float* __restrict__ labels,
    uchar_t* __restrict__ F8, uchar_t* __restrict__ lab8, float* __restrict__ out)
{
    const int row = blockIdx.x * 8 + (threadIdx.x >> 6);
    const int l = threadIdx.x & 63;
    const float4* fr = (const float4*)(feats + (size_t)row * DIM);
    const float4 a = fr[2 * l];
    const float4 b = fr[2 * l + 1];
    float ss = (a.x * a.x + a.y * a.y) + (a.z * a.z + a.w * a.w)
             + (b.x * b.x + b.y * b.y) + (b.z * b.z + b.w * b.w);
#pragma unroll
    for (int m = 32; m; m >>= 1) ss += __shfl_xor(ss, m, 64);
    const float sc16 = rsqrtf(ss) * 16.0f;   // store features x16 (e4m3 sweet spot)

    const float v[8] = {a.x, a.y, a.z, a.w, b.x, b.y, b.z, b.w};
    unsigned lo = 0, hi = 0;
#pragma unroll
    for (int k = 0; k < 4; ++k) {
        __hip_fp8_e4m3 q0(v[k] * sc16);
        __hip_fp8_e4m3 q1(v[k + 4] * sc16);
        lo |= (unsigned)q0.__x << (8 * k);
        hi |= (unsigned)q1.__x << (8 * k);
    }
    ((uint2*)(F8 + (size_t)row * DIM))[l] = make_uint2(lo, hi);

    if (l < 25) {
        const float4 lb = ((const float4*)(labels + (size_t)row * NCLS))[l];
        const float lv[4] = {lb.x, lb.y, lb.z, lb.w};
#pragma unroll
        for (int k = 0; k < 4; ++k)
            if (lv[k] > 0.5f) lab8[row] = (uchar_t)(l * 4 + k);
    }
    if (blockIdx.x == 0 && threadIdx.x == 0) out[0] = 0.0f;
}

// ---------- K2: fused sim-GEMM (MX-fp8, K=128/instr) + symmetric column-stats ----------
// 128x128 tile, 512 thr = 8 waves (2x4), 64x32/wave. K-loop: 4 steps of BK=128
// (vs 16 of BK=32 in bf16) -> 4x fewer barriers, ~2x less LDS-read traffic.
// Dual-buffered LDS (64KB, 2 blocks/CU; grid = exactly 2 generations).
// LDS slot-XOR swizzle (slot ^= row&7) applied on the GLOBAL source (linear
// LDS dest, required by global_load_lds) and on the ds_read address.
#define BM 128
#define BKB 128                 // K-bytes (fp8) per step
#define NK8 (DIM / BKB)         // 4

__global__ __launch_bounds__(512) void gemm_sim(
    const uchar_t* __restrict__ F8, const uchar_t* __restrict__ lab8,
    float* __restrict__ part_f)   // [4096 cols][64 widx=by*2+wr][4] {pmin,psum,negmax,nsum}
{
    // XCD-aware bijective swizzle: 1024 blocks, 8 XCDs, 128 blocks/XCD chunk.
    const int bid = (int)blockIdx.x;
    const int swz = (bid & 7) * 128 + (bid >> 3);
    const int bx = swz & 31, by = swz >> 5;
    const int brow = by * BM, bcol = bx * BM;
    const bool bdiag = (bx == by);

    __shared__ __align__(16) uchar_t sA8[2][BM * BKB];   // 2 x 16KB
    __shared__ __align__(16) uchar_t sB8[2][BM * BKB];   // 2 x 16KB
    const int t = threadIdx.x;
    const int w = t >> 6, l = t & 63;
    const int wr = w >> 2, wc = w & 3;          // 2x4 waves -> 64x32 each

    f32x4 acc[4][2];
    const f32x4 fz = {0.f, 0.f, 0.f, 0.f};
#pragma unroll
    for (int m = 0; m < 4; ++m)
#pragma unroll
        for (int n = 0; n < 2; ++n) acc[m][n] = fz;

    // stage one 128x128B tile per matrix: 1024 16B-slots, 2 per thread per matrix.
    // linear slot sl -> row = sl>>3, logical slot s = sl&7; global slot = s ^ (row&7)
    auto stage = [&](int buf, int kb) {
#pragma unroll
        for (int i = 0; i < 2; ++i) {
            const int sl  = i * 512 + t;
            const int row = sl >> 3, s = sl & 7;
            const int kc  = s ^ (row & 7);
            async_load16(F8 + (size_t)(brow + row) * DIM + kb + kc * 16, &sA8[buf][sl * 16]);
            async_load16(F8 + (size_t)(bcol + row) * DIM + kb + kc * 16, &sB8[buf][sl * 16]);
        }
    };

    stage(0, 0);
    asm volatile("s_waitcnt vmcnt(0)\n\ts_barrier" ::: "memory");

#pragma unroll
    for (int ks = 0; ks < NK8; ++ks) {
        const int cur = ks & 1;
        if (ks + 1 < NK8) stage(cur ^ 1, (ks + 1) * BKB);

        // fragment reads: lane l holds row (l&15), K-chunk (l>>4)*32 bytes
        // = logical slots (l>>4)*2, +1; physical slot = logical ^ (row&7)
        int8v av[4], bv[2];
#pragma unroll
        for (int m = 0; m < 4; ++m) {
            const int r  = wr * 64 + m * 16 + (l & 15);
            const int s0 = (l >> 4) * 2;
            const uint4 lo = *(const uint4*)&sA8[cur][r * BKB + ((s0    ) ^ (r & 7)) * 16];
            const uint4 hi = *(const uint4*)&sA8[cur][r * BKB + ((s0 + 1) ^ (r & 7)) * 16];
            av[m] = (int8v){(int)lo.x, (int)lo.y, (int)lo.z, (int)lo.w,
                            (int)hi.x, (int)hi.y, (int)hi.z, (int)hi.w};
        }
#pragma unroll
        for (int n = 0; n < 2; ++n) {
            const int r  = wc * 32 + n * 16 + (l & 15);
            const int s0 = (l >> 4) * 2;
            const uint4 lo = *(const uint4*)&sB8[cur][r * BKB + ((s0    ) ^ (r & 7)) * 16];
            const uint4 hi = *(const uint4*)&sB8[cur][r * BKB + ((s0 + 1) ^ (r & 7)) * 16];
            bv[n] = (int8v){(int)lo.x, (int)lo.y, (int)lo.z, (int)lo.w,
                            (int)hi.x, (int)hi.y, (int)hi.z, (int)hi.w};
        }
#pragma unroll
        for (int m = 0; m < 4; ++m)
#pragma unroll
            for (int n = 0; n < 2; ++n)
                acc[m][n] = __builtin_amdgcn_mfma_scale_f32_16x16x128_f8f6f4(
                    av[m], bv[n], acc[m][n],
                    0, 0,                 // cbsz=fp8(e4m3), blgp=fp8(e4m3)
                    0, SCL_16TH,          // A scale: byte0, 2^-4
                    0, SCL_16TH);         // B scale: byte0, 2^-4

        if (ks < NK8 - 1) {
            // tile ks+1 landed for all waves; reads of buffer cur complete (WAR)
            asm volatile("s_waitcnt vmcnt(0) lgkmcnt(0)\n\ts_barrier" ::: "memory");
        }
    }

    // ---- epilogue: per-COLUMN stats (== per-row stats by symmetry) ----
    // C/D layout: col = wc*32 + n*16 + (l&15); rows = wr*64 + m*16 + g*4 + r
    const int g = l >> 4, c = l & 15;
    const bool hi4 = g & 1, hi5 = (g >> 1) & 1;
    const int widx = by * 2 + wr;

    int rl[4][4];
#pragma unroll
    for (int m = 0; m < 4; ++m) {
        const uchar4 r4 = *(const uchar4*)(lab8 + brow + wr * 64 + m * 16 + g * 4);
        rl[m][0] = r4.x; rl[m][1] = r4.y; rl[m][2] = r4.z; rl[m][3] = r4.w;
    }
    const int growb = brow + wr * 64 + g * 4;   // + m*16 + r gives the global row

#pragma unroll
    for (int n = 0; n < 2; ++n) {
        const int gcol = bcol + wc * 32 + n * 16 + c;
        const int cl = (int)lab8[gcol];
        float pm = BIGF, nm = -BIGF, ps = 0.f, ns = 0.f;
#pragma unroll
        for (int m = 0; m < 4; ++m)
#pragma unroll
            for (int r = 0; r < 4; ++r) {
                const float s = acc[m][n][r];
                const bool same = (rl[m][r] == cl);
                const float e = __builtin_amdgcn_exp2f((same ? K_POS : K_NEG) * (s - 0.5f));
                const bool excl = bdiag && (growb + m * 16 + r == gcol);
                if (same) {
                    if (s < ONE_EPS && !excl) { pm = fminf(pm, s); ps += e; }
                } else {
                    nm = fmaxf(nm, s); ns += e;
                }
            }
        // packed reduce-scatter over g (masks 16,32): lane-g ends with
        // quantity q==g of [pm, ps, nm, ns], fully reduced over 64 rows
        float sa = hi4 ? pm : ps;
        float sb = hi4 ? nm : ns;
        const float ra = __shfl_xor(sa, 16, 64);
        const float rb = __shfl_xor(sb, 16, 64);
        const float a = hi4 ? (ps + ra) : fminf(pm, ra);
        const float b = hi4 ? (ns + rb) : fmaxf(nm, rb);
        float sc_ = hi5 ? a : b;
        const float rc = __shfl_xor(sc_, 32, 64);
        const float v = hi5 ? (hi4 ? (b + rc) : fmaxf(b, rc))
                            : (hi4 ? (a + rc) : fminf(a, rc));
        part_f[((size_t)gcol * 64 + widx) * 4 + g] = v;
    }
}

// ---------- K3: one wave per row: merge 64 partials -> row loss ----------
__global__ __launch_bounds__(256) void row_finish(
    const float4* __restrict__ part, float* __restrict__ rowloss)
{
    const int g = threadIdx.x >> 6, j = threadIdx.x & 63;
    const int i = blockIdx.x * 4 + g;
    const float4 p = part[(size_t)i * 64 + j];
    float pm = p.x, ps = p.y, nm = p.z, ns = p.w;
#pragma unroll
    for (int m = 32; m; m >>= 1) {
        pm = fminf(pm, __shfl_xor(pm, m, 64));
        nm = fmaxf(nm, __shfl_xor(nm, m, 64));
        ps += __shfl_xor(ps, m, 64);
        ns += __shfl_xor(ns, m, 64);
    }
    if (j == 0) {
        // any neg kept <=> nm + margin > pm (then neg_max = nm);
        // any pos kept <=> pm - margin < neg_max
        const bool anyneg = (nm + MARGIN > pm);
        const bool valid  = anyneg && (pm - MARGIN < nm);
        rowloss[i] = valid ? (log1pf(ps) * 0.5f + log1pf(ns) * 0.025f) : 0.0f;
    }
}

// ---------- K4: sum rowloss -> out[0] (single block, no atomics) ----------
__global__ __launch_bounds__(256) void final_reduce(
    const float* __restrict__ rowloss, float* __restrict__ out)
{
    __shared__ float red[4];
    const int t = threadIdx.x;
    const float4* rp = (const float4*)rowloss;
    float v = 0.f;
#pragma unroll
    for (int q = 0; q < 4; ++q) {
        const float4 a = rp[t + 256 * q];
        v += (a.x + a.y) + (a.z + a.w);
    }
#pragma unroll
    for (int m = 32; m; m >>= 1) v += __shfl_xor(v, m, 64);
    if ((t & 63) == 0) red[t >> 6] = v;
    __syncthreads();
    if (t == 0) out[0] = (red[0] + red[1] + red[2] + red[3]) * (1.0f / (float)B_N);
}

extern "C" void kernel_launch(void* const* d_in, const int* in_sizes, int n_in,
                              void* d_out, int out_size, void* d_ws, size_t ws_size,
                              hipStream_t stream) {
    const float* feats  = (const float*)d_in[0];
    const float* labels = (const float*)d_in[1];
    float* out = (float*)d_out;

    // ws: part float[4096*64*4] = 4MB | F8 fp8 2MB | lab u8 4KB | rowloss 16KB
    char* ws = (char*)d_ws;
    float*    part_f  = (float*)ws;
    uchar_t*  F8      = (uchar_t*)(ws + (size_t)B_N * 64 * 16);
    uchar_t*  lab8    = (uchar_t*)(ws + (size_t)B_N * 64 * 16 + (size_t)B_N * DIM);
    float*    rowloss = (float*)  (ws + (size_t)B_N * 64 * 16 + (size_t)B_N * DIM + (size_t)B_N);

    prep_kernel<<<B_N / 8, 512, 0, stream>>>(feats, labels, F8, lab8, out);
    gemm_sim<<<(B_N / BM) * (B_N / BM), 512, 0, stream>>>(F8, lab8, part_f);
    row_finish<<<B_N / 4, 256, 0, stream>>>((const float4*)part_f, rowloss);
    final_reduce<<<1, 256, 0, stream>>>(rowloss, out);
}